// Round 7
// baseline (227.698 us; speedup 1.0000x reference)
//
#include <hip/hip_runtime.h>
#include <hip/hip_bf16.h>
#include <math.h>

#define LEAKY(x) fmaxf((x), 0.01f * (x))

typedef float v2f __attribute__((ext_vector_type(2)));
typedef __bf16 bf8 __attribute__((ext_vector_type(8)));
typedef float f4 __attribute__((ext_vector_type(4)));

// Problem dims (fixed by setup_inputs): I=1024 images, C=32 curves, L=64 pts
constexpr int IMGS = 1024;
constexpr int CRV  = 32;
constexpr int LPT  = 64;

__device__ __forceinline__ void ldseg(float* dst, const float* __restrict__ src,
                                      int n, int tid, int nt) {
  for (int i = tid; i < n; i += nt) dst[i] = src[i];
}

__device__ __forceinline__ f4 leaky4(f4 x) {
  return __builtin_elementwise_max(x, x * 0.01f);
}

// sum of ring neighbors v[lane-1]+v[lane+1] via DPP wave_rol:1 / wave_ror:1.
__device__ __forceinline__ float ring_sum(float v) {
  int s = __builtin_bit_cast(int, v);
  int a = __builtin_amdgcn_update_dpp(0, s, 0x134, 0xF, 0xF, false);
  int b = __builtin_amdgcn_update_dpp(0, s, 0x13C, 0xF, 0xF, false);
  return __builtin_bit_cast(float, a) + __builtin_bit_cast(float, b);
}

// all-lanes sum within each DPP row of 16 lanes via row_ror:1/2/4/8 rotations
__device__ __forceinline__ float row_sum16(float v) {
  int s;
  s = __builtin_amdgcn_update_dpp(0, __builtin_bit_cast(int, v), 0x121, 0xF, 0xF, false);
  v += __builtin_bit_cast(float, s);
  s = __builtin_amdgcn_update_dpp(0, __builtin_bit_cast(int, v), 0x122, 0xF, 0xF, false);
  v += __builtin_bit_cast(float, s);
  s = __builtin_amdgcn_update_dpp(0, __builtin_bit_cast(int, v), 0x124, 0xF, 0xF, false);
  v += __builtin_bit_cast(float, s);
  s = __builtin_amdgcn_update_dpp(0, __builtin_bit_cast(int, v), 0x128, 0xF, 0xF, false);
  v += __builtin_bit_cast(float, s);
  return v;
}

// accurate RNE pack (prep only; has NaN handling via HIP header)
__device__ __forceinline__ unsigned bfpair(float x, float y) {
  __hip_bfloat162 h = __float22bfloat162_rn(make_float2(x, y));
  unsigned r;
  __builtin_memcpy(&r, &h, 4);
  return r;
}

// fast RNE pack for finite data: identical rounding to __float2bfloat16_rn
// (u + 0x7fff + lsb-of-target), no NaN check; single v_perm_b32 pack.
__device__ __forceinline__ unsigned bfr(float x) {
  unsigned u = __builtin_bit_cast(unsigned, x);
  return u + 0x7fffu + ((u >> 16) & 1u);
}
__device__ __forceinline__ unsigned bfpair_fast(float x, float y) {
  // dst bytes [xr2, xr3, yr2, yr3] -> sel 0x07060302 with S0=yr, S1=xr
  return __builtin_amdgcn_perm(bfr(y), bfr(x), 0x07060302u);
}

// swizzled word offset for [row][32 bf16] tiles stored as 16 words/row:
// 16B-column c placed at slot (c + (row>>1)) & 3  -> 2-way max bank aliasing
#define WOFF(pp, cc) (((pp) << 4) + ((((cc) + ((pp) >> 1)) & 3) << 2))

// ---------------- Prep kernel (1 block, trivial) ----------------
// Folds crv_mlp (ring-agg linears) into crv_lv1:  embed = M @ [x,S1,T2,1]
__device__ float w1eff_val(const float* mw, const float* mb,
                           const float* w1, const float* b1, int n, int k) {
  if (k < 8) {
    return w1[k * 32 + n] + 0.5f * w1[(8 + k) * 32 + n] + 0.25f * w1[(16 + k) * 32 + n];
  } else if (k < 16) {
    int a = k - 8;
    float s = 0.f;
    for (int i = 0; i < 8; i++)
      s += mw[a * 8 + i] * (w1[(8 + i) * 32 + n] + w1[(16 + i) * 32 + n]);
    return 0.25f * s;
  } else if (k < 24) {
    int a = k - 16;
    float s = 0.f;
    for (int i = 0; i < 8; i++) {
      float m2 = 0.f;
      for (int c = 0; c < 8; c++) m2 += mw[a * 8 + c] * mw[c * 8 + i];
      s += m2 * w1[(16 + i) * 32 + n];
    }
    return 0.0625f * s;
  } else if (k == 24) {
    float s = b1[n];
    for (int i = 0; i < 8; i++) {
      s += mb[i] * (0.5f * w1[(8 + i) * 32 + n] + 0.75f * w1[(16 + i) * 32 + n]);
      float wb = 0.f;
      for (int c = 0; c < 8; c++) wb += mb[c] * mw[c * 8 + i];
      s += 0.25f * wb * w1[(16 + i) * 32 + n];
    }
    return s;
  }
  return 0.f;
}

__global__ __launch_bounds__(256) void prep_kernel(
    const float* __restrict__ mw, const float* __restrict__ mb,
    const float* __restrict__ w1, const float* __restrict__ b1,
    const float* __restrict__ w2, const float* __restrict__ b2,
    const float* __restrict__ i1w, const float* __restrict__ i2w,
    unsigned* __restrict__ fragA1, unsigned* __restrict__ fragA2,
    float* __restrict__ fragC,
    float* __restrict__ i1wT, float* __restrict__ i2wT)
{
  const int tid = threadIdx.x;
  // A fragments: [tile(2)][lane(64)][word(4)]; lane holds A[m=lane&15][k=(lane>>4)*8+j]
  for (int idx = tid; idx < 512; idx += 256) {
    int tile = idx >> 8;
    int lane = (idx >> 2) & 63;
    int word = idx & 3;
    int n  = tile * 16 + (lane & 15);
    int k0 = (lane >> 4) * 8 + word * 2;
    fragA1[idx] = bfpair(w1eff_val(mw, mb, w1, b1, n, k0),
                         w1eff_val(mw, mb, w1, b1, n, k0 + 1));
    float u0 = (n < 24) ? w2[k0 * 24 + n] : 0.f;
    float u1 = (n < 24) ? w2[(k0 + 1) * 24 + n] : 0.f;
    fragA2[idx] = bfpair(u0, u1);
  }
  // C-operand fragments: [tile][lane][r], row = (lane>>4)*4 + r
  for (int idx = tid; idx < 512; idx += 256) {
    int tile = idx >> 8;
    int lane = (idx >> 2) & 63;
    int r = idx & 3;
    int n = tile * 16 + ((lane >> 4) & 3) * 4 + r;
    fragC[idx] = (n < 24) ? b2[n] : 0.f;
  }
  // transposed inter weights: col jd contiguous
  for (int idx = tid; idx < 576; idx += 256) {
    int jj = idx / 24, ii = idx - jj * 24;
    i1wT[idx] = i1w[ii * 24 + jj];
    i2wT[idx] = i2w[ii * 24 + jj];
  }
}

// ---------------- Kernel 1: curve level (MFMA, no barriers) ----------------
__global__ __launch_bounds__(256) void curve_kernel(
    const float* __restrict__ ct,
    const unsigned* __restrict__ fragA1, const unsigned* __restrict__ fragA2,
    const float* __restrict__ fragC,
    const float* __restrict__ i1wT, const float* __restrict__ i1b,
    const float* __restrict__ i2wT, const float* __restrict__ i2b,
    float* __restrict__ gout)
{
  __shared__ __align__(16) unsigned sX[4][1024];   // per-wave [64 p][32 k] bf16
  __shared__ __align__(16) float    srow[4][32];

  const int tid  = threadIdx.x;
  const int wave = tid >> 6;
  const int lane = tid & 63;
  const int curve = blockIdx.x * 4 + wave;

  // ---- A-operand fragment loads (issue early; 16B coalesced, L1-hot) ----
  uint4 awv[2], a2v[2];
  float4 cbv[2];
  #pragma unroll
  for (int mt = 0; mt < 2; mt++) {
    awv[mt] = *(const uint4*)(fragA1 + mt * 256 + lane * 4);
    a2v[mt] = *(const uint4*)(fragA2 + mt * 256 + lane * 4);
    cbv[mt] = *(const float4*)(fragC + mt * 256 + lane * 4);
  }

  // ---- point load + ring-sum basis ----
  const float* p = ct + ((size_t)curve * LPT + lane) * 8;
  float4 t0 = *(const float4*)p;
  float4 t1 = *(const float4*)(p + 4);
  float x[8];
  x[0] = t0.x; x[1] = t0.y; x[2] = t0.z; x[3] = t0.w;
  x[4] = t1.x; x[5] = t1.y; x[6] = t1.z; x[7] = t1.w;
  float s1[8], t2[8];
  #pragma unroll
  for (int i = 0; i < 8; i++) s1[i] = ring_sum(x[i]);
  #pragma unroll
  for (int i = 0; i < 8; i++) t2[i] = ring_sum(s1[i]);

  // ---- write X row: [x(8) | S1(8) | T2(8) | 1, 0...] bf16, swizzled ----
  unsigned* Xw = &sX[wave][0];
  {
    uint4 wv;
    wv.x = bfpair_fast(x[0], x[1]);  wv.y = bfpair_fast(x[2], x[3]);
    wv.z = bfpair_fast(x[4], x[5]);  wv.w = bfpair_fast(x[6], x[7]);
    *(uint4*)&Xw[WOFF(lane, 0)] = wv;
    wv.x = bfpair_fast(s1[0], s1[1]); wv.y = bfpair_fast(s1[2], s1[3]);
    wv.z = bfpair_fast(s1[4], s1[5]); wv.w = bfpair_fast(s1[6], s1[7]);
    *(uint4*)&Xw[WOFF(lane, 1)] = wv;
    wv.x = bfpair_fast(t2[0], t2[1]); wv.y = bfpair_fast(t2[2], t2[3]);
    wv.z = bfpair_fast(t2[4], t2[5]); wv.w = bfpair_fast(t2[6], t2[7]);
    *(uint4*)&Xw[WOFF(lane, 2)] = wv;
    wv.x = 0x00003f80u; wv.y = 0u; wv.z = 0u; wv.w = 0u;   // bf16(1.0), zeros
    *(uint4*)&Xw[WOFF(lane, 3)] = wv;
  }
  __builtin_amdgcn_wave_barrier();

  const int q   = lane >> 4;   // quad
  const int c16 = lane & 15;

  // ---- lv1: H1^T = W1eff @ U^T ----
  f4 d[2][4];
  {
    bf8 bx[4];
    #pragma unroll
    for (int nt = 0; nt < 4; nt++)
      bx[nt] = __builtin_bit_cast(bf8, *(const uint4*)&Xw[WOFF(c16 + nt * 16, q)]);
    const f4 z = (f4){0.f, 0.f, 0.f, 0.f};
    #pragma unroll
    for (int mt = 0; mt < 2; mt++) {
      bf8 aw = __builtin_bit_cast(bf8, awv[mt]);
      #pragma unroll
      for (int nt = 0; nt < 4; nt++)
        d[mt][nt] = __builtin_amdgcn_mfma_f32_16x16x32_bf16(aw, bx[nt], z, 0, 0, 0);
    }
  }
  // leaky (packed) + write H1^T back (reuse Xw, layout [point][k=h1dim])
  #pragma unroll
  for (int mt = 0; mt < 2; mt++) {
    #pragma unroll
    for (int nt = 0; nt < 4; nt++) {
      f4 v = leaky4(d[mt][nt]);
      const int prow = nt * 16 + c16;
      const int word = WOFF(prow, mt * 2 + (q >> 1)) + (q & 1) * 2;
      uint2 pk; pk.x = bfpair_fast(v.x, v.y); pk.y = bfpair_fast(v.z, v.w);
      *(uint2*)&Xw[word] = pk;
    }
  }
  __builtin_amdgcn_wave_barrier();

  // ---- lv2: H2^T = W2t @ H1^T + b2 (C operand) ----
  f4 d2[2][4];
  {
    bf8 bh[4];
    #pragma unroll
    for (int nt = 0; nt < 4; nt++)
      bh[nt] = __builtin_bit_cast(bf8, *(const uint4*)&Xw[WOFF(c16 + nt * 16, q)]);
    #pragma unroll
    for (int mt = 0; mt < 2; mt++) {
      bf8 a2 = __builtin_bit_cast(bf8, a2v[mt]);
      f4 cb_ = __builtin_bit_cast(f4, cbv[mt]);
      #pragma unroll
      for (int nt = 0; nt < 4; nt++)
        d2[mt][nt] = __builtin_amdgcn_mfma_f32_16x16x32_bf16(a2, bh[nt], cb_, 0, 0, 0);
    }
  }

  // ---- leaky (packed) + f4 tree-sum + DPP row-sum mean over 64 points ----
  float m8[2][4];
  #pragma unroll
  for (int mt = 0; mt < 2; mt++) {
    f4 t = leaky4(d2[mt][0]) + leaky4(d2[mt][1]);
    t = t + leaky4(d2[mt][2]);
    t = t + leaky4(d2[mt][3]);
    #pragma unroll
    for (int r = 0; r < 4; r++)
      m8[mt][r] = row_sum16(t[r]) * (1.0f / 64.0f);
  }
  if (c16 == 0) {
    f4 v0 = (f4){m8[0][0], m8[0][1], m8[0][2], m8[0][3]};
    *(f4*)&srow[wave][q * 4] = v0;
    if (q < 2) {
      f4 v1 = (f4){m8[1][0], m8[1][1], m8[1][2], m8[1][3]};
      *(f4*)&srow[wave][16 + q * 4] = v1;
    }
  }
  __builtin_amdgcn_wave_barrier();

  // ---- inter MLP (fp32, transposed-column weight loads) ----
  float sv[24];
  #pragma unroll
  for (int i = 0; i < 24; i++) sv[i] = srow[wave][i];

  const int jd = (lane < 24) ? lane : 0;
  float a = i1b[jd];
  #pragma unroll
  for (int t = 0; t < 6; t++) {
    float4 wv = *(const float4*)&i1wT[jd * 24 + t * 4];
    a += sv[t * 4 + 0] * wv.x + sv[t * 4 + 1] * wv.y
       + sv[t * 4 + 2] * wv.z + sv[t * 4 + 3] * wv.w;
  }
  a = LEAKY(a);
  if (lane < 24) srow[wave][lane] = a;
  __builtin_amdgcn_wave_barrier();

  float av[24];
  #pragma unroll
  for (int i = 0; i < 24; i++) av[i] = srow[wave][i];

  float o = i2b[jd];
  #pragma unroll
  for (int t = 0; t < 6; t++) {
    float4 wv = *(const float4*)&i2wT[jd * 24 + t * 4];
    o += av[t * 4 + 0] * wv.x + av[t * 4 + 1] * wv.y
       + av[t * 4 + 2] * wv.z + av[t * 4 + 3] * wv.w;
  }
  o = LEAKY(o);

  if (lane < 24) gout[(size_t)curve * 24 + lane] = o;
}

// ---------------- Kernel 2: fused image level (unchanged) ----------------
__global__ __launch_bounds__(768) void image_kernel(
    const float* __restrict__ cors, const float* __restrict__ gin,
    const float* __restrict__ cw,  const float* __restrict__ cb,
    const float* __restrict__ g1w, const float* __restrict__ g1b,
    const float* __restrict__ g2w, const float* __restrict__ g2b,
    const float* __restrict__ g3w, const float* __restrict__ g3b,
    const float* __restrict__ m1w, const float* __restrict__ m1b,
    const float* __restrict__ m2w, const float* __restrict__ m2b,
    const float* __restrict__ m3w, const float* __restrict__ m3b,
    float* __restrict__ out)
{
  __shared__ __align__(16) float sCorsP[CRV * CRV * 8];
  __shared__ __align__(16) float sG0[CRV * 24], sG1[CRV * 24], sG2[CRV * 24];
  __shared__ __align__(16) float sHa[CRV * 24], sHb[CRV * 24];
  __shared__ float sW1[1728], sW2[576], sW3[576];
  __shared__ float sT[96];

  const int tid = threadIdx.x;
  const int img = blockIdx.x;
  const int j = tid / 24;
  const int d = tid - j * 24;

  {
    const float* cbase = cors + (size_t)img * (CRV * CRV * 5);
    for (int idx = tid; idx < CRV * CRV * 5; idx += 768) {
      int jj = idx / 160;
      int r  = idx - jj * 160;
      int k  = r / 5;
      int c  = r - k * 5;
      sCorsP[(jj * CRV + k) * 8 + c] = cbase[idx];
    }
  }
  sG0[tid] = gin[(size_t)img * (CRV * 24) + tid];
  ldseg(sW1, g1w, 1728, tid, 768);
  ldseg(sW2, g2w, 576, tid, 768);
  ldseg(sW3, g3w, 576, tid, 768);
  float wc0 = cw[0 * 24 + d], wc1 = cw[1 * 24 + d], wc2 = cw[2 * 24 + d];
  float wc3 = cw[3 * 24 + d], wc4 = cw[4 * 24 + d];
  float cbd = cb[d];
  float g1bd = g1b[d], g2bd = g2b[d], g3bd = g3b[d];
  __syncthreads();

  float corv[CRV];
  #pragma unroll
  for (int k = 0; k < CRV; k++) {
    const float* cr = &sCorsP[(j * CRV + k) * 8];
    float4 qq = *(const float4*)cr;
    float q4 = cr[4];
    float v = cbd + qq.x * wc0 + qq.y * wc1 + qq.z * wc2 + qq.w * wc3 + q4 * wc4;
    corv[k] = LEAKY(v);
  }
  {
    float t1 = 0.0f;
    #pragma unroll
    for (int k = 0; k < CRV; k++) t1 += sG0[k * 24 + d] * corv[k];
    sG1[j * 24 + d] = t1;
  }
  __syncthreads();
  {
    float t2 = 0.0f;
    #pragma unroll
    for (int k = 0; k < CRV; k++) t2 += sG1[k * 24 + d] * corv[k];
    sG2[j * 24 + d] = t2;
  }
  __syncthreads();
  {
    float v = g1bd;
    #pragma unroll
    for (int i = 0; i < 24; i++) v += sG0[j * 24 + i] * sW1[i * 24 + d];
    #pragma unroll
    for (int i = 0; i < 24; i++) v += sG1[j * 24 + i] * sW1[(24 + i) * 24 + d];
    #pragma unroll
    for (int i = 0; i < 24; i++) v += sG2[j * 24 + i] * sW1[(48 + i) * 24 + d];
    sHa[j * 24 + d] = LEAKY(v);
  }
  __syncthreads();
  {
    float v = g2bd;
    #pragma unroll
    for (int i = 0; i < 24; i++) v += sHa[j * 24 + i] * sW2[i * 24 + d];
    sHb[j * 24 + d] = LEAKY(v);
  }
  __syncthreads();
  {
    float v = g3bd;
    #pragma unroll
    for (int i = 0; i < 24; i++) v += sHb[j * 24 + i] * sW3[i * 24 + d];
    sHa[j * 24 + d] = LEAKY(v);
  }
  __syncthreads();
  if (tid < 24) {
    float s = 0.0f;
    #pragma unroll
    for (int k = 0; k < CRV; k++) s += sHa[k * 24 + tid];
    sT[tid] = s * (1.0f / CRV);
  }
  __syncthreads();
  if (tid < 18) {
    float v = m1b[tid];
    #pragma unroll
    for (int i = 0; i < 24; i++) v += sT[i] * m1w[i * 18 + tid];
    sT[32 + tid] = LEAKY(v);
  }
  __syncthreads();
  if (tid < 12) {
    float v = m2b[tid];
    #pragma unroll
    for (int i = 0; i < 18; i++) v += sT[32 + i] * m2w[i * 12 + tid];
    sT[56 + tid] = LEAKY(v);
  }
  __syncthreads();
  if (tid < 6) {
    float v = m3b[tid];
    #pragma unroll
    for (int i = 0; i < 12; i++) v += sT[56 + i] * m3w[i * 6 + tid];
    out[img * 6 + tid] = 1.0f / (1.0f + expf(-v));
  }
}

extern "C" void kernel_launch(void* const* d_in, const int* in_sizes, int n_in,
                              void* d_out, int out_size, void* d_ws, size_t ws_size,
                              hipStream_t stream) {
  const float* ct   = (const float*)d_in[0];
  const float* cors = (const float*)d_in[2];
  const float* mw  = (const float*)d_in[3];
  const float* mb  = (const float*)d_in[4];
  const float* w1  = (const float*)d_in[5];
  const float* b1  = (const float*)d_in[6];
  const float* w2  = (const float*)d_in[7];
  const float* b2  = (const float*)d_in[8];
  const float* i1w = (const float*)d_in[9];
  const float* i1b = (const float*)d_in[10];
  const float* i2w = (const float*)d_in[11];
  const float* i2b = (const float*)d_in[12];

  const float *cw, *cb, *g1w, *g1b, *g2w, *g2b, *g3w, *g3b;
  const float *m1w, *m1b, *m2w, *m2b, *m3w, *m3b;
  if (in_sizes[13] == 120) {
    cw  = (const float*)d_in[13]; cb  = (const float*)d_in[14];
    g1w = (const float*)d_in[15]; g1b = (const float*)d_in[16];
    g2w = (const float*)d_in[17]; g2b = (const float*)d_in[18];
    g3w = (const float*)d_in[19]; g3b = (const float*)d_in[20];
    m1w = (const float*)d_in[21]; m1b = (const float*)d_in[22];
    m2w = (const float*)d_in[23]; m2b = (const float*)d_in[24];
    m3w = (const float*)d_in[25]; m3b = (const float*)d_in[26];
  } else {
    g1w = (const float*)d_in[13]; g1b = (const float*)d_in[14];
    g2w = (const float*)d_in[15]; g2b = (const float*)d_in[16];
    g3w = (const float*)d_in[17]; g3b = (const float*)d_in[18];
    m1w = (const float*)d_in[19]; m1b = (const float*)d_in[20];
    m2w = (const float*)d_in[21]; m2b = (const float*)d_in[22];
    m3w = (const float*)d_in[23]; m3b = (const float*)d_in[24];
    cw  = (const float*)d_in[25]; cb  = (const float*)d_in[26];
  }

  float* wsf = (float*)d_ws;
  float* group = wsf;                                  // [I*C,24] = 786432 floats
  const size_t base = (size_t)IMGS * CRV * 24;         // 786432 (16B-aligned)
  unsigned* fragA1 = (unsigned*)(wsf + base);          // 512 words
  unsigned* fragA2 = fragA1 + 512;                     // 512
  float*    fragC  = (float*)(fragA2 + 512);           // 512
  float*    i1wT   = fragC + 512;                      // 576
  float*    i2wT   = i1wT + 576;                       // 576
  float* out = (float*)d_out;

  prep_kernel<<<1, 256, 0, stream>>>(mw, mb, w1, b1, w2, b2, i1w, i2w,
                                     fragA1, fragA2, fragC, i1wT, i2wT);
  curve_kernel<<<(IMGS * CRV) / 4, 256, 0, stream>>>(
      ct, fragA1, fragA2, fragC, i1wT, i1b, i2wT, i2b, group);
  image_kernel<<<IMGS, 768, 0, stream>>>(
      cors, group, cw, cb, g1w, g1b, g2w, g2b, g3w, g3b,
      m1w, m1b, m2w, m2b, m3w, m3b, out);
}

// Round 8
// 220.034 us; speedup vs baseline: 1.0348x; 1.0348x over previous
//
#include <hip/hip_runtime.h>
#include <hip/hip_bf16.h>
#include <math.h>

#define LEAKY(x) fmaxf((x), 0.01f * (x))

typedef float v2f __attribute__((ext_vector_type(2)));
typedef __bf16 bf8 __attribute__((ext_vector_type(8)));
typedef float f4 __attribute__((ext_vector_type(4)));

// Problem dims (fixed by setup_inputs): I=1024 images, C=32 curves, L=64 pts
constexpr int IMGS = 1024;
constexpr int CRV  = 32;
constexpr int LPT  = 64;

__device__ __forceinline__ void ldseg(float* dst, const float* __restrict__ src,
                                      int n, int tid, int nt) {
  for (int i = tid; i < n; i += nt) dst[i] = src[i];
}

__device__ __forceinline__ f4 leaky4(f4 x) {
  return __builtin_elementwise_max(x, x * 0.01f);
}

// sum of ring neighbors v[lane-1]+v[lane+1] via DPP wave_rol:1 / wave_ror:1.
__device__ __forceinline__ float ring_sum(float v) {
  int s = __builtin_bit_cast(int, v);
  int a = __builtin_amdgcn_update_dpp(0, s, 0x134, 0xF, 0xF, false);
  int b = __builtin_amdgcn_update_dpp(0, s, 0x13C, 0xF, 0xF, false);
  return __builtin_bit_cast(float, a) + __builtin_bit_cast(float, b);
}

// all-lanes sum within each DPP row of 16 lanes via row_ror:1/2/4/8 rotations
__device__ __forceinline__ float row_sum16(float v) {
  int s;
  s = __builtin_amdgcn_update_dpp(0, __builtin_bit_cast(int, v), 0x121, 0xF, 0xF, false);
  v += __builtin_bit_cast(float, s);
  s = __builtin_amdgcn_update_dpp(0, __builtin_bit_cast(int, v), 0x122, 0xF, 0xF, false);
  v += __builtin_bit_cast(float, s);
  s = __builtin_amdgcn_update_dpp(0, __builtin_bit_cast(int, v), 0x124, 0xF, 0xF, false);
  v += __builtin_bit_cast(float, s);
  s = __builtin_amdgcn_update_dpp(0, __builtin_bit_cast(int, v), 0x128, 0xF, 0xF, false);
  v += __builtin_bit_cast(float, s);
  return v;
}

// accurate RNE pack (prep only)
__device__ __forceinline__ unsigned bfpair(float x, float y) {
  __hip_bfloat162 h = __float22bfloat162_rn(make_float2(x, y));
  unsigned r;
  __builtin_memcpy(&r, &h, 4);
  return r;
}

// fast RNE pack for finite data: identical rounding to __float2bfloat16_rn
__device__ __forceinline__ unsigned bfr(float x) {
  unsigned u = __builtin_bit_cast(unsigned, x);
  return u + 0x7fffu + ((u >> 16) & 1u);
}
__device__ __forceinline__ unsigned bfpair_fast(float x, float y) {
  return __builtin_amdgcn_perm(bfr(y), bfr(x), 0x07060302u);
}

// swizzled word offset for [row][32 bf16] tiles stored as 16 words/row
#define WOFF(pp, cc) (((pp) << 4) + ((((cc) + ((pp) >> 1)) & 3) << 2))

// ---------------- Prep kernel (1 block, trivial) ----------------
__device__ float w1eff_val(const float* mw, const float* mb,
                           const float* w1, const float* b1, int n, int k) {
  if (k < 8) {
    return w1[k * 32 + n] + 0.5f * w1[(8 + k) * 32 + n] + 0.25f * w1[(16 + k) * 32 + n];
  } else if (k < 16) {
    int a = k - 8;
    float s = 0.f;
    for (int i = 0; i < 8; i++)
      s += mw[a * 8 + i] * (w1[(8 + i) * 32 + n] + w1[(16 + i) * 32 + n]);
    return 0.25f * s;
  } else if (k < 24) {
    int a = k - 16;
    float s = 0.f;
    for (int i = 0; i < 8; i++) {
      float m2 = 0.f;
      for (int c = 0; c < 8; c++) m2 += mw[a * 8 + c] * mw[c * 8 + i];
      s += m2 * w1[(16 + i) * 32 + n];
    }
    return 0.0625f * s;
  } else if (k == 24) {
    float s = b1[n];
    for (int i = 0; i < 8; i++) {
      s += mb[i] * (0.5f * w1[(8 + i) * 32 + n] + 0.75f * w1[(16 + i) * 32 + n]);
      float wb = 0.f;
      for (int c = 0; c < 8; c++) wb += mb[c] * mw[c * 8 + i];
      s += 0.25f * wb * w1[(16 + i) * 32 + n];
    }
    return s;
  }
  return 0.f;
}

__global__ __launch_bounds__(256) void prep_kernel(
    const float* __restrict__ mw, const float* __restrict__ mb,
    const float* __restrict__ w1, const float* __restrict__ b1,
    const float* __restrict__ w2, const float* __restrict__ b2,
    const float* __restrict__ i1w, const float* __restrict__ i2w,
    unsigned* __restrict__ fragA1, unsigned* __restrict__ fragA2,
    float* __restrict__ fragC,
    float* __restrict__ i1wT, float* __restrict__ i2wT)
{
  const int tid = threadIdx.x;
  for (int idx = tid; idx < 512; idx += 256) {
    int tile = idx >> 8;
    int lane = (idx >> 2) & 63;
    int word = idx & 3;
    int n  = tile * 16 + (lane & 15);
    int k0 = (lane >> 4) * 8 + word * 2;
    fragA1[idx] = bfpair(w1eff_val(mw, mb, w1, b1, n, k0),
                         w1eff_val(mw, mb, w1, b1, n, k0 + 1));
    float u0 = (n < 24) ? w2[k0 * 24 + n] : 0.f;
    float u1 = (n < 24) ? w2[(k0 + 1) * 24 + n] : 0.f;
    fragA2[idx] = bfpair(u0, u1);
  }
  for (int idx = tid; idx < 512; idx += 256) {
    int tile = idx >> 8;
    int lane = (idx >> 2) & 63;
    int r = idx & 3;
    int n = tile * 16 + ((lane >> 4) & 3) * 4 + r;
    fragC[idx] = (n < 24) ? b2[n] : 0.f;
  }
  for (int idx = tid; idx < 576; idx += 256) {
    int jj = idx / 24, ii = idx - jj * 24;
    i1wT[idx] = i1w[ii * 24 + jj];
    i2wT[idx] = i2w[ii * 24 + jj];
  }
}

// ---------------- Kernel 1: curve level (MFMA, 2 curves/wave) ----------------
// One wave handles curves c0,c1 with independent register chains interleaved
// -> in-wave ILP hides the serial LDS/MFMA/VMEM latency chain. A-fragments,
// wave barriers, inter-MLP and launch overhead amortize over 2 curves.
__global__ __launch_bounds__(256) void curve_kernel(
    const float* __restrict__ ct,
    const unsigned* __restrict__ fragA1, const unsigned* __restrict__ fragA2,
    const float* __restrict__ fragC,
    const float* __restrict__ i1wT, const float* __restrict__ i1b,
    const float* __restrict__ i2wT, const float* __restrict__ i2b,
    float* __restrict__ gout)
{
  __shared__ __align__(16) unsigned sX[4][2][1024];  // [wave][curve][64p x 16w]
  __shared__ __align__(16) float    srow[4][2][32];

  const int tid  = threadIdx.x;
  const int wave = tid >> 6;
  const int lane = tid & 63;
  const int curve0 = blockIdx.x * 8 + wave * 2;      // even; +1 = second curve

  // ---- A/C fragment loads (once per wave, 2 curves) ----
  uint4 awv[2], a2v[2];
  float4 cbv[2];
  #pragma unroll
  for (int mt = 0; mt < 2; mt++) {
    awv[mt] = *(const uint4*)(fragA1 + mt * 256 + lane * 4);
    a2v[mt] = *(const uint4*)(fragA2 + mt * 256 + lane * 4);
    cbv[mt] = *(const float4*)(fragC + mt * 256 + lane * 4);
  }

  // ---- point loads (both curves issued before any dependent math) ----
  const float* pA = ct + ((size_t)curve0 * LPT + lane) * 8;
  const float* pB = pA + LPT * 8;
  float4 a0 = *(const float4*)pA;
  float4 a1 = *(const float4*)(pA + 4);
  float4 b0 = *(const float4*)pB;
  float4 b1v = *(const float4*)(pB + 4);

  float xA[8], xB[8];
  xA[0] = a0.x; xA[1] = a0.y; xA[2] = a0.z; xA[3] = a0.w;
  xA[4] = a1.x; xA[5] = a1.y; xA[6] = a1.z; xA[7] = a1.w;
  xB[0] = b0.x; xB[1] = b0.y; xB[2] = b0.z; xB[3] = b0.w;
  xB[4] = b1v.x; xB[5] = b1v.y; xB[6] = b1v.z; xB[7] = b1v.w;

  float s1A[8], t2A[8], s1B[8], t2B[8];
  #pragma unroll
  for (int i = 0; i < 8; i++) s1A[i] = ring_sum(xA[i]);
  #pragma unroll
  for (int i = 0; i < 8; i++) s1B[i] = ring_sum(xB[i]);
  #pragma unroll
  for (int i = 0; i < 8; i++) t2A[i] = ring_sum(s1A[i]);
  #pragma unroll
  for (int i = 0; i < 8; i++) t2B[i] = ring_sum(s1B[i]);

  unsigned* Xw0 = &sX[wave][0][0];
  unsigned* Xw1 = &sX[wave][1][0];
  {
    uint4 wv;
    wv.x = bfpair_fast(xA[0], xA[1]);  wv.y = bfpair_fast(xA[2], xA[3]);
    wv.z = bfpair_fast(xA[4], xA[5]);  wv.w = bfpair_fast(xA[6], xA[7]);
    *(uint4*)&Xw0[WOFF(lane, 0)] = wv;
    wv.x = bfpair_fast(s1A[0], s1A[1]); wv.y = bfpair_fast(s1A[2], s1A[3]);
    wv.z = bfpair_fast(s1A[4], s1A[5]); wv.w = bfpair_fast(s1A[6], s1A[7]);
    *(uint4*)&Xw0[WOFF(lane, 1)] = wv;
    wv.x = bfpair_fast(t2A[0], t2A[1]); wv.y = bfpair_fast(t2A[2], t2A[3]);
    wv.z = bfpair_fast(t2A[4], t2A[5]); wv.w = bfpair_fast(t2A[6], t2A[7]);
    *(uint4*)&Xw0[WOFF(lane, 2)] = wv;
    wv.x = 0x00003f80u; wv.y = 0u; wv.z = 0u; wv.w = 0u;
    *(uint4*)&Xw0[WOFF(lane, 3)] = wv;

    wv.x = bfpair_fast(xB[0], xB[1]);  wv.y = bfpair_fast(xB[2], xB[3]);
    wv.z = bfpair_fast(xB[4], xB[5]);  wv.w = bfpair_fast(xB[6], xB[7]);
    *(uint4*)&Xw1[WOFF(lane, 0)] = wv;
    wv.x = bfpair_fast(s1B[0], s1B[1]); wv.y = bfpair_fast(s1B[2], s1B[3]);
    wv.z = bfpair_fast(s1B[4], s1B[5]); wv.w = bfpair_fast(s1B[6], s1B[7]);
    *(uint4*)&Xw1[WOFF(lane, 1)] = wv;
    wv.x = bfpair_fast(t2B[0], t2B[1]); wv.y = bfpair_fast(t2B[2], t2B[3]);
    wv.z = bfpair_fast(t2B[4], t2B[5]); wv.w = bfpair_fast(t2B[6], t2B[7]);
    *(uint4*)&Xw1[WOFF(lane, 2)] = wv;
    wv.x = 0x00003f80u; wv.y = 0u; wv.z = 0u; wv.w = 0u;
    *(uint4*)&Xw1[WOFF(lane, 3)] = wv;
  }
  __builtin_amdgcn_wave_barrier();

  const int q   = lane >> 4;
  const int c16 = lane & 15;

  // ---- lv1 + repack, both curves (independent chains, one barrier) ----
  #pragma unroll
  for (int cv = 0; cv < 2; cv++) {
    unsigned* Xw = cv ? Xw1 : Xw0;
    f4 d[2][4];
    bf8 bx[4];
    #pragma unroll
    for (int nt = 0; nt < 4; nt++)
      bx[nt] = __builtin_bit_cast(bf8, *(const uint4*)&Xw[WOFF(c16 + nt * 16, q)]);
    const f4 z = (f4){0.f, 0.f, 0.f, 0.f};
    #pragma unroll
    for (int mt = 0; mt < 2; mt++) {
      bf8 aw = __builtin_bit_cast(bf8, awv[mt]);
      #pragma unroll
      for (int nt = 0; nt < 4; nt++)
        d[mt][nt] = __builtin_amdgcn_mfma_f32_16x16x32_bf16(aw, bx[nt], z, 0, 0, 0);
    }
    #pragma unroll
    for (int mt = 0; mt < 2; mt++) {
      #pragma unroll
      for (int nt = 0; nt < 4; nt++) {
        f4 v = leaky4(d[mt][nt]);
        const int prow = nt * 16 + c16;
        const int word = WOFF(prow, mt * 2 + (q >> 1)) + (q & 1) * 2;
        uint2 pk; pk.x = bfpair_fast(v.x, v.y); pk.y = bfpair_fast(v.z, v.w);
        *(uint2*)&Xw[word] = pk;
      }
    }
  }
  __builtin_amdgcn_wave_barrier();

  // ---- lv2 + epilogue, both curves ----
  #pragma unroll
  for (int cv = 0; cv < 2; cv++) {
    unsigned* Xw = cv ? Xw1 : Xw0;
    f4 d2[2][4];
    bf8 bh[4];
    #pragma unroll
    for (int nt = 0; nt < 4; nt++)
      bh[nt] = __builtin_bit_cast(bf8, *(const uint4*)&Xw[WOFF(c16 + nt * 16, q)]);
    #pragma unroll
    for (int mt = 0; mt < 2; mt++) {
      bf8 a2 = __builtin_bit_cast(bf8, a2v[mt]);
      f4 cb_ = __builtin_bit_cast(f4, cbv[mt]);
      #pragma unroll
      for (int nt = 0; nt < 4; nt++)
        d2[mt][nt] = __builtin_amdgcn_mfma_f32_16x16x32_bf16(a2, bh[nt], cb_, 0, 0, 0);
    }
    float m8[2][4];
    #pragma unroll
    for (int mt = 0; mt < 2; mt++) {
      f4 t = leaky4(d2[mt][0]) + leaky4(d2[mt][1]);
      t = t + leaky4(d2[mt][2]);
      t = t + leaky4(d2[mt][3]);
      #pragma unroll
      for (int r = 0; r < 4; r++)
        m8[mt][r] = row_sum16(t[r]) * (1.0f / 64.0f);
    }
    if (c16 == 0) {
      f4 v0 = (f4){m8[0][0], m8[0][1], m8[0][2], m8[0][3]};
      *(f4*)&srow[wave][cv][q * 4] = v0;
      if (q < 2) {
        f4 v1 = (f4){m8[1][0], m8[1][1], m8[1][2], m8[1][3]};
        *(f4*)&srow[wave][cv][16 + q * 4] = v1;
      }
    }
  }
  __builtin_amdgcn_wave_barrier();

  // ---- inter MLP: lanes 0-31 -> curve A, lanes 32-63 -> curve B ----
  const int half = lane >> 5;
  const int l32  = lane & 31;
  const int jd   = (l32 < 24) ? l32 : 0;
  float* srw = &srow[wave][half][0];

  float sv[24];
  #pragma unroll
  for (int i = 0; i < 24; i++) sv[i] = srw[i];

  float a = i1b[jd];
  #pragma unroll
  for (int t = 0; t < 6; t++) {
    float4 wv = *(const float4*)&i1wT[jd * 24 + t * 4];
    a += sv[t * 4 + 0] * wv.x + sv[t * 4 + 1] * wv.y
       + sv[t * 4 + 2] * wv.z + sv[t * 4 + 3] * wv.w;
  }
  a = LEAKY(a);
  if (l32 < 24) srw[l32] = a;
  __builtin_amdgcn_wave_barrier();

  float av[24];
  #pragma unroll
  for (int i = 0; i < 24; i++) av[i] = srw[i];

  float o = i2b[jd];
  #pragma unroll
  for (int t = 0; t < 6; t++) {
    float4 wv = *(const float4*)&i2wT[jd * 24 + t * 4];
    o += av[t * 4 + 0] * wv.x + av[t * 4 + 1] * wv.y
       + av[t * 4 + 2] * wv.z + av[t * 4 + 3] * wv.w;
  }
  o = LEAKY(o);

  if (l32 < 24) gout[(size_t)(curve0 + half) * 24 + l32] = o;
}

// ---------------- Kernel 2: fused image level (unchanged) ----------------
__global__ __launch_bounds__(768) void image_kernel(
    const float* __restrict__ cors, const float* __restrict__ gin,
    const float* __restrict__ cw,  const float* __restrict__ cb,
    const float* __restrict__ g1w, const float* __restrict__ g1b,
    const float* __restrict__ g2w, const float* __restrict__ g2b,
    const float* __restrict__ g3w, const float* __restrict__ g3b,
    const float* __restrict__ m1w, const float* __restrict__ m1b,
    const float* __restrict__ m2w, const float* __restrict__ m2b,
    const float* __restrict__ m3w, const float* __restrict__ m3b,
    float* __restrict__ out)
{
  __shared__ __align__(16) float sCorsP[CRV * CRV * 8];
  __shared__ __align__(16) float sG0[CRV * 24], sG1[CRV * 24], sG2[CRV * 24];
  __shared__ __align__(16) float sHa[CRV * 24], sHb[CRV * 24];
  __shared__ float sW1[1728], sW2[576], sW3[576];
  __shared__ float sT[96];

  const int tid = threadIdx.x;
  const int img = blockIdx.x;
  const int j = tid / 24;
  const int d = tid - j * 24;

  {
    const float* cbase = cors + (size_t)img * (CRV * CRV * 5);
    for (int idx = tid; idx < CRV * CRV * 5; idx += 768) {
      int jj = idx / 160;
      int r  = idx - jj * 160;
      int k  = r / 5;
      int c  = r - k * 5;
      sCorsP[(jj * CRV + k) * 8 + c] = cbase[idx];
    }
  }
  sG0[tid] = gin[(size_t)img * (CRV * 24) + tid];
  ldseg(sW1, g1w, 1728, tid, 768);
  ldseg(sW2, g2w, 576, tid, 768);
  ldseg(sW3, g3w, 576, tid, 768);
  float wc0 = cw[0 * 24 + d], wc1 = cw[1 * 24 + d], wc2 = cw[2 * 24 + d];
  float wc3 = cw[3 * 24 + d], wc4 = cw[4 * 24 + d];
  float cbd = cb[d];
  float g1bd = g1b[d], g2bd = g2b[d], g3bd = g3b[d];
  __syncthreads();

  float corv[CRV];
  #pragma unroll
  for (int k = 0; k < CRV; k++) {
    const float* cr = &sCorsP[(j * CRV + k) * 8];
    float4 qq = *(const float4*)cr;
    float q4 = cr[4];
    float v = cbd + qq.x * wc0 + qq.y * wc1 + qq.z * wc2 + qq.w * wc3 + q4 * wc4;
    corv[k] = LEAKY(v);
  }
  {
    float t1 = 0.0f;
    #pragma unroll
    for (int k = 0; k < CRV; k++) t1 += sG0[k * 24 + d] * corv[k];
    sG1[j * 24 + d] = t1;
  }
  __syncthreads();
  {
    float t2 = 0.0f;
    #pragma unroll
    for (int k = 0; k < CRV; k++) t2 += sG1[k * 24 + d] * corv[k];
    sG2[j * 24 + d] = t2;
  }
  __syncthreads();
  {
    float v = g1bd;
    #pragma unroll
    for (int i = 0; i < 24; i++) v += sG0[j * 24 + i] * sW1[i * 24 + d];
    #pragma unroll
    for (int i = 0; i < 24; i++) v += sG1[j * 24 + i] * sW1[(24 + i) * 24 + d];
    #pragma unroll
    for (int i = 0; i < 24; i++) v += sG2[j * 24 + i] * sW1[(48 + i) * 24 + d];
    sHa[j * 24 + d] = LEAKY(v);
  }
  __syncthreads();
  {
    float v = g2bd;
    #pragma unroll
    for (int i = 0; i < 24; i++) v += sHa[j * 24 + i] * sW2[i * 24 + d];
    sHb[j * 24 + d] = LEAKY(v);
  }
  __syncthreads();
  {
    float v = g3bd;
    #pragma unroll
    for (int i = 0; i < 24; i++) v += sHb[j * 24 + i] * sW3[i * 24 + d];
    sHa[j * 24 + d] = LEAKY(v);
  }
  __syncthreads();
  if (tid < 24) {
    float s = 0.0f;
    #pragma unroll
    for (int k = 0; k < CRV; k++) s += sHa[k * 24 + tid];
    sT[tid] = s * (1.0f / CRV);
  }
  __syncthreads();
  if (tid < 18) {
    float v = m1b[tid];
    #pragma unroll
    for (int i = 0; i < 24; i++) v += sT[i] * m1w[i * 18 + tid];
    sT[32 + tid] = LEAKY(v);
  }
  __syncthreads();
  if (tid < 12) {
    float v = m2b[tid];
    #pragma unroll
    for (int i = 0; i < 18; i++) v += sT[32 + i] * m2w[i * 12 + tid];
    sT[56 + tid] = LEAKY(v);
  }
  __syncthreads();
  if (tid < 6) {
    float v = m3b[tid];
    #pragma unroll
    for (int i = 0; i < 12; i++) v += sT[56 + i] * m3w[i * 6 + tid];
    out[img * 6 + tid] = 1.0f / (1.0f + expf(-v));
  }
}

extern "C" void kernel_launch(void* const* d_in, const int* in_sizes, int n_in,
                              void* d_out, int out_size, void* d_ws, size_t ws_size,
                              hipStream_t stream) {
  const float* ct   = (const float*)d_in[0];
  const float* cors = (const float*)d_in[2];
  const float* mw  = (const float*)d_in[3];
  const float* mb  = (const float*)d_in[4];
  const float* w1  = (const float*)d_in[5];
  const float* b1  = (const float*)d_in[6];
  const float* w2  = (const float*)d_in[7];
  const float* b2  = (const float*)d_in[8];
  const float* i1w = (const float*)d_in[9];
  const float* i1b = (const float*)d_in[10];
  const float* i2w = (const float*)d_in[11];
  const float* i2b = (const float*)d_in[12];

  const float *cw, *cb, *g1w, *g1b, *g2w, *g2b, *g3w, *g3b;
  const float *m1w, *m1b, *m2w, *m2b, *m3w, *m3b;
  if (in_sizes[13] == 120) {
    cw  = (const float*)d_in[13]; cb  = (const float*)d_in[14];
    g1w = (const float*)d_in[15]; g1b = (const float*)d_in[16];
    g2w = (const float*)d_in[17]; g2b = (const float*)d_in[18];
    g3w = (const float*)d_in[19]; g3b = (const float*)d_in[20];
    m1w = (const float*)d_in[21]; m1b = (const float*)d_in[22];
    m2w = (const float*)d_in[23]; m2b = (const float*)d_in[24];
    m3w = (const float*)d_in[25]; m3b = (const float*)d_in[26];
  } else {
    g1w = (const float*)d_in[13]; g1b = (const float*)d_in[14];
    g2w = (const float*)d_in[15]; g2b = (const float*)d_in[16];
    g3w = (const float*)d_in[17]; g3b = (const float*)d_in[18];
    m1w = (const float*)d_in[19]; m1b = (const float*)d_in[20];
    m2w = (const float*)d_in[21]; m2b = (const float*)d_in[22];
    m3w = (const float*)d_in[23]; m3b = (const float*)d_in[24];
    cw  = (const float*)d_in[25]; cb  = (const float*)d_in[26];
  }

  float* wsf = (float*)d_ws;
  float* group = wsf;                                  // [I*C,24] = 786432 floats
  const size_t base = (size_t)IMGS * CRV * 24;
  unsigned* fragA1 = (unsigned*)(wsf + base);
  unsigned* fragA2 = fragA1 + 512;
  float*    fragC  = (float*)(fragA2 + 512);
  float*    i1wT   = fragC + 512;
  float*    i2wT   = i1wT + 576;
  float* out = (float*)d_out;

  prep_kernel<<<1, 256, 0, stream>>>(mw, mb, w1, b1, w2, b2, i1w, i2w,
                                     fragA1, fragA2, fragC, i1wT, i2wT);
  curve_kernel<<<(IMGS * CRV) / 8, 256, 0, stream>>>(
      ct, fragA1, fragA2, fragC, i1wT, i1b, i2wT, i2b, group);
  image_kernel<<<IMGS, 768, 0, stream>>>(
      cors, group, cw, cb, g1w, g1b, g2w, g2b, g3w, g3b,
      m1w, m1b, m2w, m2b, m3w, m3b, out);
}